// Round 2
// baseline (72.065 us; speedup 1.0000x reference)
//
#include <hip/hip_runtime.h>

#define IMG_H 256
#define IMG_W 256
#define OUT_J 64   // W / PS

// Closed form of the 4-qubit circuit:
//   u_q = cos(chrom[q]) * cos(pixel_q)
//   out0 = u1*u2*u3, out1 = u0*u1, out2 = u0*u1*u2, out3 = u0*u1*u2*u3
// Output[b,q,r,j] = sqrt( H(b,r,j,q)^2 + V(b,r,j,q)^2 )
//   H patch: img[b, r, 4j..4j+3]   (a float4)
//   V patch: img[b, 4j..4j+3, r]   (column reads -> staged via LDS tile)

__global__ __launch_bounds__(256) void quanv_kernel(
    const float* __restrict__ img,
    const float* __restrict__ chrom,
    float* __restrict__ out)
{
    // Vertical-source tile: rows 64*jt .. +63, cols r0 .. r0+63 of image b.
    // Pad to 65 floats/row: read pattern tileV[4*jj+k][rr] -> bank (4jj+k+rr)%32,
    // 2-way conflict only (free per m136).
    __shared__ float tileV[64][65];

    const int blk = blockIdx.x;
    const int jt = blk & 3;          // j-tile (16 j each)
    const int rt = (blk >> 2) & 3;   // r-tile (64 r each)
    const int b  = blk >> 4;         // image
    const int r0 = rt << 6;
    const int c0 = jt << 6;          // first pixel-row of vertical tile = 4*(16*jt)
    const int t  = threadIdx.x;

    const float* imgb = img + b * (IMG_H * IMG_W);

    // chromosome cosines (uniform across threads, 4 cached scalar loads)
    const float cc0 = __cosf(chrom[0]);
    const float cc1 = __cosf(chrom[1]);
    const float cc2 = __cosf(chrom[2]);
    const float cc3 = __cosf(chrom[3]);

    // stage vertical tile: tileV[vr][vc] = imgb[(c0+vr)*W + r0+vc]
#pragma unroll
    for (int it = 0; it < 4; ++it) {
        int idx = it * 256 + t;       // 0..1023 float4-slots
        int vr  = idx >> 4;           // 0..63
        int vc4 = idx & 15;           // 0..15
        const float4 v = *reinterpret_cast<const float4*>(
            imgb + (c0 + vr) * IMG_W + r0 + (vc4 << 2));
        float* d = &tileV[vr][vc4 << 2];
        d[0] = v.x; d[1] = v.y; d[2] = v.z; d[3] = v.w;
    }
    __syncthreads();

    const float4* imgb4 = reinterpret_cast<const float4*>(imgb);

#pragma unroll
    for (int it = 0; it < 4; ++it) {
        int p  = it * 256 + t;        // 0..1023 output positions (rr, jj)
        int jj = p & 15;              // 0..15
        int rr = p >> 4;              // 0..63
        int r  = r0 + rr;
        int j  = (jt << 4) + jj;

        // horizontal patch: 4 consecutive pixels = one float4
        float4 hp = imgb4[r * (IMG_W / 4) + j];

        // vertical patch from LDS
        float v0 = tileV[(jj << 2) + 0][rr];
        float v1 = tileV[(jj << 2) + 1][rr];
        float v2 = tileV[(jj << 2) + 2][rr];
        float v3 = tileV[(jj << 2) + 3][rr];

        float uh0 = __cosf(hp.x) * cc0;
        float uh1 = __cosf(hp.y) * cc1;
        float uh2 = __cosf(hp.z) * cc2;
        float uh3 = __cosf(hp.w) * cc3;

        float uv0 = __cosf(v0) * cc0;
        float uv1 = __cosf(v1) * cc1;
        float uv2 = __cosf(v2) * cc2;
        float uv3 = __cosf(v3) * cc3;

        float h1 = uh0 * uh1;
        float h2 = h1 * uh2;
        float h3 = h2 * uh3;
        float h0 = uh1 * (uh2 * uh3);

        float w1 = uv0 * uv1;
        float w2 = w1 * uv2;
        float w3 = w2 * uv3;
        float w0 = uv1 * (uv2 * uv3);

        float o0 = sqrtf(h0 * h0 + w0 * w0);
        float o1 = sqrtf(h1 * h1 + w1 * w1);
        float o2 = sqrtf(h2 * h2 + w2 * w2);
        float o3 = sqrtf(h3 * h3 + w3 * w3);

        // out[b][q][r][j], q-stride = 256*64
        float* ob = out + ((b * 4) * IMG_H + r) * OUT_J + j;
        ob[0 * IMG_H * OUT_J] = o0;
        ob[1 * IMG_H * OUT_J] = o1;
        ob[2 * IMG_H * OUT_J] = o2;
        ob[3 * IMG_H * OUT_J] = o3;
    }
}

extern "C" void kernel_launch(void* const* d_in, const int* in_sizes, int n_in,
                              void* d_out, int out_size, void* d_ws, size_t ws_size,
                              hipStream_t stream) {
    const float* x     = (const float*)d_in[0];  // (64,1,256,256) f32
    const float* chrom = (const float*)d_in[1];  // (4,) f32
    float* o           = (float*)d_out;          // (64,4,256,64) f32

    quanv_kernel<<<1024, 256, 0, stream>>>(x, chrom, o);
}

// Round 3
// 72.025 us; speedup vs baseline: 1.0006x; 1.0006x over previous
//
#include <hip/hip_runtime.h>

#define IMG_H 256
#define IMG_W 256
#define OUT_J 64   // W / PS

// Closed form of the 4-qubit circuit:
//   u_q = cos(chrom[q]) * cos(pixel_q)
//   out0 = u1*u2*u3, out1 = u0*u1, out2 = u0*u1*u2, out3 = u0*u1*u2*u3
// Output[b,q,r,j] = sqrt( H(b,r,j,q)^2 + V(b,r,j,q)^2 )
//   H patch: img[b, r, 4j..4j+3]   (row-contiguous -> float4 loads)
//   V patch: img[b, 4j..4j+3, r]   (column reads -> staged via padded LDS tile)
//
// 512 threads/block, 2 output positions (one j-pair) per thread:
//   524288 threads = 8192 waves = 32 waves/CU (full occupancy target).

__global__ __launch_bounds__(512, 8) void quanv_kernel(
    const float* __restrict__ img,
    const float* __restrict__ chrom,
    float* __restrict__ out)
{
    // V-source tile: image rows c0..c0+63, cols r0..r0+63.
    // Pad row to 65 floats: bank = (row + col) % 32 for reads -> worst 2-way (free).
    __shared__ float tileV[64][65];

    const int blk = blockIdx.x;
    const int jt = blk & 3;          // j-tile (16 j each)
    const int rt = (blk >> 2) & 3;   // r-tile (64 r each)
    const int b  = blk >> 4;         // image
    const int r0 = rt << 6;
    const int c0 = jt << 6;          // first pixel-row of V tile = 4*(16*jt)
    const int t  = threadIdx.x;

    const float* imgb = img + b * (IMG_H * IMG_W);

    const float cc0 = __cosf(chrom[0]);
    const float cc1 = __cosf(chrom[1]);
    const float cc2 = __cosf(chrom[2]);
    const float cc3 = __cosf(chrom[3]);

    // stage V tile: tileV[vr][vc] = imgb[(c0+vr)*W + r0+vc]; 1024 float4 slots / 512 threads
#pragma unroll
    for (int it = 0; it < 2; ++it) {
        int idx = it * 512 + t;       // 0..1023
        int vr  = idx >> 4;           // 0..63
        int vc4 = idx & 15;           // 0..15
        const float4 v = *reinterpret_cast<const float4*>(
            imgb + (c0 + vr) * IMG_W + r0 + (vc4 << 2));
        float* d = &tileV[vr][vc4 << 2];
        d[0] = v.x; d[1] = v.y; d[2] = v.z; d[3] = v.w;
    }
    __syncthreads();

    // thread -> (row rr, j-pair jp)
    const int jp = t & 7;             // 0..7  (pair of j's)
    const int rr = t >> 3;            // 0..63
    const int r  = r0 + rr;
    const int hb = (jt << 6) + (jp << 3);   // first pixel col of the 8-pixel strip

    // H: 8 consecutive pixels = 2 float4
    const float4 h0v = *reinterpret_cast<const float4*>(imgb + r * IMG_W + hb);
    const float4 h1v = *reinterpret_cast<const float4*>(imgb + r * IMG_W + hb + 4);

    // V: 8 pixels from LDS, rows 8jp..8jp+7, col rr
    const int vrow = jp << 3;
    float va0 = tileV[vrow + 0][rr];
    float va1 = tileV[vrow + 1][rr];
    float va2 = tileV[vrow + 2][rr];
    float va3 = tileV[vrow + 3][rr];
    float vb0 = tileV[vrow + 4][rr];
    float vb1 = tileV[vrow + 5][rr];
    float vb2 = tileV[vrow + 6][rr];
    float vb3 = tileV[vrow + 7][rr];

    // ---- position m=0 (j = 16jt + 2jp) ----
    float uh0 = __cosf(h0v.x) * cc0, uh1 = __cosf(h0v.y) * cc1;
    float uh2 = __cosf(h0v.z) * cc2, uh3 = __cosf(h0v.w) * cc3;
    float uv0 = __cosf(va0) * cc0,  uv1 = __cosf(va1) * cc1;
    float uv2 = __cosf(va2) * cc2,  uv3 = __cosf(va3) * cc3;

    float h1 = uh0 * uh1, h2 = h1 * uh2, h3 = h2 * uh3, hh0 = uh1 * (uh2 * uh3);
    float w1 = uv0 * uv1, w2 = w1 * uv2, w3 = w2 * uv3, ww0 = uv1 * (uv2 * uv3);

    float o0a = sqrtf(hh0 * hh0 + ww0 * ww0);
    float o1a = sqrtf(h1 * h1 + w1 * w1);
    float o2a = sqrtf(h2 * h2 + w2 * w2);
    float o3a = sqrtf(h3 * h3 + w3 * w3);

    // ---- position m=1 (j+1) ----
    uh0 = __cosf(h1v.x) * cc0; uh1 = __cosf(h1v.y) * cc1;
    uh2 = __cosf(h1v.z) * cc2; uh3 = __cosf(h1v.w) * cc3;
    uv0 = __cosf(vb0) * cc0;   uv1 = __cosf(vb1) * cc1;
    uv2 = __cosf(vb2) * cc2;   uv3 = __cosf(vb3) * cc3;

    h1 = uh0 * uh1; h2 = h1 * uh2; h3 = h2 * uh3; hh0 = uh1 * (uh2 * uh3);
    w1 = uv0 * uv1; w2 = w1 * uv2; w3 = w2 * uv3; ww0 = uv1 * (uv2 * uv3);

    float o0b = sqrtf(hh0 * hh0 + ww0 * ww0);
    float o1b = sqrtf(h1 * h1 + w1 * w1);
    float o2b = sqrtf(h2 * h2 + w2 * w2);
    float o3b = sqrtf(h3 * h3 + w3 * w3);

    // stores: float2 per q-plane at out[b][q][r][16jt + 2jp]
    float* ob = out + ((b * 4) * IMG_H + r) * OUT_J + (jt << 4) + (jp << 1);
    const int qs = IMG_H * OUT_J;
    *reinterpret_cast<float2*>(ob + 0 * qs) = make_float2(o0a, o0b);
    *reinterpret_cast<float2*>(ob + 1 * qs) = make_float2(o1a, o1b);
    *reinterpret_cast<float2*>(ob + 2 * qs) = make_float2(o2a, o2b);
    *reinterpret_cast<float2*>(ob + 3 * qs) = make_float2(o3a, o3b);
}

extern "C" void kernel_launch(void* const* d_in, const int* in_sizes, int n_in,
                              void* d_out, int out_size, void* d_ws, size_t ws_size,
                              hipStream_t stream) {
    const float* x     = (const float*)d_in[0];  // (64,1,256,256) f32
    const float* chrom = (const float*)d_in[1];  // (4,) f32
    float* o           = (float*)d_out;          // (64,4,256,64) f32

    quanv_kernel<<<1024, 512, 0, stream>>>(x, chrom, o);
}